// Round 2
// baseline (17.923 us; speedup 1.0000x reference)
//
#include <hip/hip_runtime.h>
#include <hip/hip_bf16.h>

// B=1024, D=128, T=0.07
//   out[b,n] = exp( (feat[b] . feat[idx[b,n]]) / T )
// Pipeline:
//   k0 split:    feat(fp32) -> feat_hi, feat_lo (bf16, RNE) in ws
//   k1 gram_exp: E[b,j] = exp(G[b,j]/T), G via 3-term bf16-split MFMA
//                (ah*bh + al*bh + ah*bl accumulated in fp32; err ~1e-5)
//   k2 gather:   out[o] = E[b, idx[o]]  (pure coalesced gather)
// Gram symmetry makes any global transpose in the MFMA layout benign, and
// identical A/B fragment load patterns make any k-permutation benign.

constexpr int BDIM = 1024;
constexpr int KD   = 128;
constexpr int NCOL = 1023;
#define INV_T 14.285714285714286f

typedef __bf16 bf16x8 __attribute__((ext_vector_type(8)));
typedef float  f32x4  __attribute__((ext_vector_type(4)));

__device__ inline unsigned short f2bf_rne(float x) {
    unsigned u = __builtin_bit_cast(unsigned, x);
    unsigned r = (u + 0x7FFFu + ((u >> 16) & 1u)) >> 16;
    return (unsigned short)r;
}

__device__ inline void gload_lds16(const void* g, void* lds) {
    __builtin_amdgcn_global_load_lds(
        (const __attribute__((address_space(1))) void*)g,
        (__attribute__((address_space(3))) void*)lds, 16, 0, 0);
}

// ---- k0: fp32 -> bf16 hi/lo split (131072 elems, float4-vectorized) ----
__global__ __launch_bounds__(256) void split_kernel(const float* __restrict__ feat,
                                                    unsigned short* __restrict__ fh,
                                                    unsigned short* __restrict__ fl) {
    const int i = blockIdx.x * 256 + threadIdx.x;     // float4 index, 32768 total
    const float4 v = reinterpret_cast<const float4*>(feat)[i];
    ushort4 h, l;
    const float* p = &v.x;
    unsigned short* ph = &h.x;
    unsigned short* pl = &l.x;
    #pragma unroll
    for (int c = 0; c < 4; ++c) {
        unsigned short hb = f2bf_rne(p[c]);
        float hf = __builtin_bit_cast(float, (unsigned)hb << 16);
        ph[c] = hb;
        pl[c] = f2bf_rne(p[c] - hf);
    }
    reinterpret_cast<ushort4*>(fh)[i] = h;
    reinterpret_cast<ushort4*>(fl)[i] = l;
}

// ---- k1: 64x64 Gram tile via bf16-split MFMA, exp fused, E to ws ----
// LDS: 4 tiles [64][128] bf16 (Ah, Al, Bh, Bl) = 64 KiB, XOR-swizzled
// content via pre-swizzled global source (global_load_lds writes linearly).
__global__ __launch_bounds__(256) void gram_exp(const unsigned short* __restrict__ fh,
                                                const unsigned short* __restrict__ fl,
                                                float* __restrict__ E) {
    __shared__ unsigned short smem[4][64][128];   // 65536 B

    const int t    = threadIdx.x;
    const int wv   = t >> 6;
    const int ln   = t & 63;
    const int tile = blockIdx.x;                  // 16x16 tiles of 64x64
    const int tr   = (tile >> 4) * 64;
    const int tc   = (tile & 15) * 64;

    // Stage 4 x 16KB tiles. Each wave owns chunks [wv*4, wv*4+4) per tile.
    // Linear LDS byte chunk*1024 + l*16 == row (chunk*4 + l>>4), col (l&15)*16.
    // Source col is XOR-swizzled so reads can apply byte ^ ((row&7)<<4).
    {
        const unsigned short* srcs[4] = { fh + (size_t)tr * KD, fl + (size_t)tr * KD,
                                          fh + (size_t)tc * KD, fl + (size_t)tc * KD };
        const int r   = (wv * 4) * 4 + (ln >> 4);       // row of first chunk
        const int cb  = (ln & 15) * 16;                 // dest byte col
        #pragma unroll
        for (int s = 0; s < 4; ++s) {
            const char* src = (const char*)srcs[s];
            char* dst = (char*)&smem[s][0][0] + (wv * 4) * 1024;
            #pragma unroll
            for (int c = 0; c < 4; ++c) {
                const int rr  = r + c * 4;
                const int scb = cb ^ ((rr & 7) << 4);
                gload_lds16(src + (size_t)rr * 256 + scb, dst + c * 1024);
            }
        }
    }
    __syncthreads();

    // Wave quadrant: rows [wr, wr+32), cols [wc, wc+32); 2x2 16x16 subtiles.
    const int wr = (wv >> 1) * 32;
    const int wc = (wv & 1) * 32;
    const int lrow = ln & 15;
    const int lk   = (ln >> 4) * 16;                    // k byte offset within 64

    f32x4 acc[2][2] = {};
    #pragma unroll
    for (int kk = 0; kk < 4; ++kk) {
        bf16x8 ah[2], al[2], bh[2], bl[2];
        #pragma unroll
        for (int i = 0; i < 2; ++i) {
            const int ra = wr + i * 16 + lrow;
            const int rb = wc + i * 16 + lrow;
            const int ba = kk * 64 + lk;
            ah[i] = *(const bf16x8*)((const char*)&smem[0][0][0] + ra * 256 + (ba ^ ((ra & 7) << 4)));
            al[i] = *(const bf16x8*)((const char*)&smem[1][0][0] + ra * 256 + (ba ^ ((ra & 7) << 4)));
            bh[i] = *(const bf16x8*)((const char*)&smem[2][0][0] + rb * 256 + (ba ^ ((rb & 7) << 4)));
            bl[i] = *(const bf16x8*)((const char*)&smem[3][0][0] + rb * 256 + (ba ^ ((rb & 7) << 4)));
        }
        #pragma unroll
        for (int i = 0; i < 2; ++i)
            #pragma unroll
            for (int j = 0; j < 2; ++j) {
                acc[i][j] = __builtin_amdgcn_mfma_f32_16x16x32_bf16(ah[i], bh[j], acc[i][j], 0, 0, 0);
                acc[i][j] = __builtin_amdgcn_mfma_f32_16x16x32_bf16(al[i], bh[j], acc[i][j], 0, 0, 0);
                acc[i][j] = __builtin_amdgcn_mfma_f32_16x16x32_bf16(ah[i], bl[j], acc[i][j], 0, 0, 0);
            }
    }

    // Epilogue: C/D layout col=lane&15, row=(lane>>4)*4+q (m89). exp fused.
    #pragma unroll
    for (int i = 0; i < 2; ++i) {
        #pragma unroll
        for (int q = 0; q < 4; ++q) {
            const int row = tr + wr + i * 16 + (ln >> 4) * 4 + q;
            #pragma unroll
            for (int j = 0; j < 2; ++j) {
                const int col = tc + wc + j * 16 + (ln & 15);
                E[(size_t)row * BDIM + col] = __expf(acc[i][j][q] * INV_T);
            }
        }
    }
}

// ---- k2: coalesced gather. 1023 blocks x 256 thr x 4 elems = 1024*1023 ----
__global__ __launch_bounds__(256) void gather_k(const float* __restrict__ E,
                                                const int* __restrict__ idx,
                                                float* __restrict__ out) {
    const int base = (blockIdx.x * 256 + threadIdx.x) * 4;
    #pragma unroll
    for (int u = 0; u < 4; ++u) {
        const int o = base + u;
        const int b = o / NCOL;                   // compiler magic-mul
        out[o] = E[(size_t)b * BDIM + idx[o]];
    }
}

// ---- fallback (tiny ws): one block per row, wave-per-output dot ----
__global__ __launch_bounds__(256) void direct_row(const float* __restrict__ feat,
                                                  const int* __restrict__ idx,
                                                  float* __restrict__ out) {
    __shared__ float sA[KD];
    const int b = blockIdx.x;
    const int t = threadIdx.x;
    if (t < KD) sA[t] = feat[(size_t)b * KD + t];
    __syncthreads();
    const int lane = t & 63;
    const int wave = t >> 6;
    const float2 a = *reinterpret_cast<const float2*>(&sA[lane * 2]);
    for (int n = wave; n < NCOL; n += 4) {
        const size_t o = (size_t)b * NCOL + n;
        const int j = idx[o];
        const float2 v = *reinterpret_cast<const float2*>(&feat[(size_t)j * KD + lane * 2]);
        float s = a.x * v.x + a.y * v.y;
        #pragma unroll
        for (int off = 32; off > 0; off >>= 1) s += __shfl_xor(s, off);
        if (lane == 0) out[o] = __expf(s * INV_T);
    }
}

extern "C" void kernel_launch(void* const* d_in, const int* in_sizes, int n_in,
                              void* d_out, int out_size, void* d_ws, size_t ws_size,
                              hipStream_t stream) {
    const float* feat = (const float*)d_in[0];
    const int* idx = (const int*)d_in[2];
    float* out = (float*)d_out;

    const size_t need = 512 * 1024 + (size_t)BDIM * BDIM * sizeof(float);  // 4.5 MiB
    if (ws_size >= need) {
        unsigned short* fh = (unsigned short*)d_ws;
        unsigned short* fl = fh + (size_t)BDIM * KD;
        float* E = (float*)((char*)d_ws + 512 * 1024);
        split_kernel<<<128, 256, 0, stream>>>(feat, fh, fl);
        gram_exp<<<256, 256, 0, stream>>>(fh, fl, E);
        gather_k<<<1023, 256, 0, stream>>>(E, idx, out);
    } else {
        direct_row<<<BDIM, 256, 0, stream>>>(feat, idx, out);
    }
}